// Round 1
// baseline (570.704 us; speedup 1.0000x reference)
//
#include <hip/hip_runtime.h>
#include <math.h>

#define NN 50000
#define EE 800000
#define ET (EE + NN)      // edges + self loops
#define F_IN 128
#define HEADS 8
#define HID 16
#define C1 (HEADS * HID)  // 128
#define CLASSES 40
#define NEG_SLOPE 0.2f

// ---------------- GEMM1: h1 = x @ W1   [N,128] x [128,128] ----------------
// block = 128 threads, handles 4 rows; thread = (row r = tid>>5, colgroup cg = tid&31 -> cols 4cg..4cg+3)
__global__ void gemm1_kernel(const float* __restrict__ x, const float* __restrict__ W1,
                             float* __restrict__ h1) {
    __shared__ float xs[4][F_IN];
    const int tid = threadIdx.x;
    const int n0 = blockIdx.x * 4;
    // stage 4 rows of x
    for (int idx = tid; idx < 4 * F_IN; idx += 128) {
        int r = idx >> 7, k = idx & 127;
        xs[r][k] = x[(size_t)(n0 + r) * F_IN + k];
    }
    __syncthreads();
    const int r = tid >> 5;
    const int cg = tid & 31;
    float4 acc = make_float4(0.f, 0.f, 0.f, 0.f);
    const float* wp = W1 + 4 * cg;
    #pragma unroll 8
    for (int k = 0; k < F_IN; ++k) {
        float xv = xs[r][k];
        float4 w = *(const float4*)(wp + (size_t)k * C1);
        acc.x += xv * w.x; acc.y += xv * w.y; acc.z += xv * w.z; acc.w += xv * w.w;
    }
    *(float4*)(h1 + (size_t)(n0 + r) * C1 + 4 * cg) = acc;
}

// ---------------- attention logits layer 1: e = <h1[n,h,:], a[h,:]> ----------------
__global__ void elogit1_kernel(const float* __restrict__ h1, const float* __restrict__ a_src,
                               const float* __restrict__ a_dst,
                               float* __restrict__ e_src, float* __restrict__ e_dst) {
    int t = blockIdx.x * blockDim.x + threadIdx.x;
    if (t >= NN * HEADS) return;
    int n = t >> 3, hd = t & 7;
    const float* hp = h1 + (size_t)n * C1 + hd * HID;
    const float* as = a_src + hd * HID;
    const float* ad = a_dst + hd * HID;
    float ss = 0.f, sd = 0.f;
    #pragma unroll
    for (int c = 0; c < HID; ++c) {
        float hv = hp[c];
        ss += hv * as[c];
        sd += hv * ad[c];
    }
    e_src[t] = ss;
    e_dst[t] = sd;
}

// ---------------- CSR build ----------------
__global__ void count_kernel(const int* __restrict__ ei, int* __restrict__ deg) {
    int e = blockIdx.x * blockDim.x + threadIdx.x;
    if (e >= ET) return;
    int d = (e < EE) ? ei[EE + e] : (e - EE);
    atomicAdd(&deg[d], 1);
}

// 2-level exclusive scan over deg[NN] -> rowptr
__global__ void scan1_kernel(const int* __restrict__ deg, int* __restrict__ rowptr,
                             int* __restrict__ bsum) {
    __shared__ int sh[256];
    const int tid = threadIdx.x;
    const int base = blockIdx.x * 1024 + tid * 4;
    int v[4], s[4];
    #pragma unroll
    for (int j = 0; j < 4; ++j) v[j] = (base + j < NN) ? deg[base + j] : 0;
    s[0] = v[0]; s[1] = s[0] + v[1]; s[2] = s[1] + v[2]; s[3] = s[2] + v[3];
    int T = s[3];
    sh[tid] = T;
    __syncthreads();
    for (int off = 1; off < 256; off <<= 1) {
        int xv = (tid >= off) ? sh[tid - off] : 0;
        __syncthreads();
        sh[tid] += xv;
        __syncthreads();
    }
    int excl = sh[tid] - T;
    #pragma unroll
    for (int j = 0; j < 4; ++j)
        if (base + j < NN) rowptr[base + j] = excl + s[j] - v[j];
    if (tid == 255) bsum[blockIdx.x] = sh[255];
}

__global__ void scan2_kernel(int* __restrict__ bsum, int nchunks) {
    __shared__ int sh[64];
    const int tid = threadIdx.x;
    int v = (tid < nchunks) ? bsum[tid] : 0;
    sh[tid] = v;
    __syncthreads();
    for (int off = 1; off < 64; off <<= 1) {
        int xv = (tid >= off) ? sh[tid - off] : 0;
        __syncthreads();
        sh[tid] += xv;
        __syncthreads();
    }
    if (tid < nchunks) bsum[tid] = sh[tid] - v;  // exclusive
}

__global__ void scan3_kernel(int* __restrict__ rowptr, const int* __restrict__ bsum,
                             int* __restrict__ cursor) {
    int i = blockIdx.x * blockDim.x + threadIdx.x;
    if (i >= NN) return;
    int rp = rowptr[i] + bsum[i >> 10];
    rowptr[i] = rp;
    cursor[i] = rp;
}

__global__ void fill_kernel(const int* __restrict__ ei, int* __restrict__ cursor,
                            int* __restrict__ csr) {
    int e = blockIdx.x * blockDim.x + threadIdx.x;
    if (e >= ET) return;
    int s, d;
    if (e < EE) { s = ei[e]; d = ei[EE + e]; } else { s = d = e - EE; }
    int p = atomicAdd(&cursor[d], 1);
    csr[p] = s;
}

// ---------------- layer-1 aggregation (softmax over in-edges, weighted sum, +bias, ELU) ----
// one block (128 threads) per dst node; thread = (head = tid>>4, ch = tid&15)
__global__ void agg1_kernel(const float* __restrict__ h1, const float* __restrict__ e_src,
                            const float* __restrict__ e_dst, const int* __restrict__ rowptr,
                            const int* __restrict__ deg, const int* __restrict__ csr,
                            const float* __restrict__ b1, float* __restrict__ hmid) {
    const int d = blockIdx.x;
    const int tid = threadIdx.x;
    const int hd = tid >> 4;
    const int start = rowptr[d];
    const int cnt = deg[d];
    const float ed = e_dst[(size_t)d * HEADS + hd];

    float m = -1e30f;
    for (int i = 0; i < cnt; ++i) {
        int s = csr[start + i];
        float al = e_src[(size_t)s * HEADS + hd] + ed;
        al = (al > 0.f) ? al : NEG_SLOPE * al;
        m = fmaxf(m, al);
    }
    float denom = 0.f, acc = 0.f;
    for (int i = 0; i < cnt; ++i) {
        int s = csr[start + i];
        float al = e_src[(size_t)s * HEADS + hd] + ed;
        al = (al > 0.f) ? al : NEG_SLOPE * al;
        float p = __expf(al - m);
        denom += p;
        acc += p * h1[(size_t)s * C1 + tid];
    }
    float o = acc / (denom + 1e-16f) + b1[tid];
    o = (o > 0.f) ? o : expm1f(o);  // ELU
    hmid[(size_t)d * C1 + tid] = o;
}

// ---------------- GEMM2: h2 = hmid @ W2  [N,128] x [128,40] ----------------
// block = 320 threads = 8 rows x 40 cols
__global__ void gemm2_kernel(const float* __restrict__ hmid, const float* __restrict__ W2,
                             float* __restrict__ h2) {
    __shared__ float xs[8][F_IN];
    const int tid = threadIdx.x;
    const int n0 = blockIdx.x * 8;
    for (int idx = tid; idx < 8 * F_IN; idx += 320) {
        int r = idx >> 7, k = idx & 127;
        xs[r][k] = hmid[(size_t)(n0 + r) * F_IN + k];
    }
    __syncthreads();
    const int r = tid / 40;
    const int c = tid % 40;
    float acc = 0.f;
    #pragma unroll 8
    for (int k = 0; k < F_IN; ++k)
        acc += xs[r][k] * W2[(size_t)k * CLASSES + c];
    h2[(size_t)(n0 + r) * CLASSES + c] = acc;
}

__global__ void elogit2_kernel(const float* __restrict__ h2, const float* __restrict__ a_src,
                               const float* __restrict__ a_dst,
                               float* __restrict__ e_src, float* __restrict__ e_dst) {
    int n = blockIdx.x * blockDim.x + threadIdx.x;
    if (n >= NN) return;
    const float* hp = h2 + (size_t)n * CLASSES;
    float ss = 0.f, sd = 0.f;
    #pragma unroll
    for (int c = 0; c < CLASSES; ++c) {
        float hv = hp[c];
        ss += hv * a_src[c];
        sd += hv * a_dst[c];
    }
    e_src[n] = ss;
    e_dst[n] = sd;
}

// ---------------- layer-2 aggregation -> output ----------------
// one block (64 threads) per dst node; lanes 0..39 own channels
__global__ void agg2_kernel(const float* __restrict__ h2, const float* __restrict__ e_src,
                            const float* __restrict__ e_dst, const int* __restrict__ rowptr,
                            const int* __restrict__ deg, const int* __restrict__ csr,
                            const float* __restrict__ b2, float* __restrict__ out) {
    const int d = blockIdx.x;
    const int c = threadIdx.x;
    const int start = rowptr[d];
    const int cnt = deg[d];
    const float ed = e_dst[d];

    float m = -1e30f;
    for (int i = 0; i < cnt; ++i) {
        int s = csr[start + i];
        float al = e_src[s] + ed;
        al = (al > 0.f) ? al : NEG_SLOPE * al;
        m = fmaxf(m, al);
    }
    float denom = 0.f, acc = 0.f;
    for (int i = 0; i < cnt; ++i) {
        int s = csr[start + i];
        float al = e_src[s] + ed;
        al = (al > 0.f) ? al : NEG_SLOPE * al;
        float p = __expf(al - m);
        denom += p;
        if (c < CLASSES) acc += p * h2[(size_t)s * CLASSES + c];
    }
    if (c < CLASSES)
        out[(size_t)d * CLASSES + c] = acc / (denom + 1e-16f) + b2[c];
}

extern "C" void kernel_launch(void* const* d_in, const int* in_sizes, int n_in,
                              void* d_out, int out_size, void* d_ws, size_t ws_size,
                              hipStream_t stream) {
    const float* x      = (const float*)d_in[0];
    const int*   ei     = (const int*)d_in[1];
    const float* W1     = (const float*)d_in[2];
    const float* a_src1 = (const float*)d_in[3];
    const float* a_dst1 = (const float*)d_in[4];
    const float* b1     = (const float*)d_in[5];
    const float* W2     = (const float*)d_in[6];
    const float* a_src2 = (const float*)d_in[7];
    const float* a_dst2 = (const float*)d_in[8];
    const float* b2     = (const float*)d_in[9];
    float* out = (float*)d_out;

    char* ws = (char*)d_ws;
    size_t off = 0;
    auto alloc = [&](size_t bytes) { char* p = ws + off; off += (bytes + 255) & ~(size_t)255; return p; };
    float* h1     = (float*)alloc((size_t)NN * C1 * 4);
    float* hmid   = (float*)alloc((size_t)NN * C1 * 4);
    float* h2     = (float*)alloc((size_t)NN * CLASSES * 4);
    float* e_src1 = (float*)alloc((size_t)NN * HEADS * 4);
    float* e_dst1 = (float*)alloc((size_t)NN * HEADS * 4);
    float* e_src2 = (float*)alloc((size_t)NN * 4);
    float* e_dst2 = (float*)alloc((size_t)NN * 4);
    int*   deg    = (int*)alloc((size_t)NN * 4);
    int*   rowptr = (int*)alloc((size_t)NN * 4);
    int*   cursor = (int*)alloc((size_t)NN * 4);
    int*   csr    = (int*)alloc((size_t)ET * 4);
    int*   bsum   = (int*)alloc(256 * 4);

    hipMemsetAsync(deg, 0, (size_t)NN * 4, stream);

    gemm1_kernel<<<NN / 4, 128, 0, stream>>>(x, W1, h1);
    elogit1_kernel<<<(NN * HEADS + 255) / 256, 256, 0, stream>>>(h1, a_src1, a_dst1, e_src1, e_dst1);

    count_kernel<<<(ET + 255) / 256, 256, 0, stream>>>(ei, deg);
    const int nchunks = (NN + 1023) / 1024;  // 49
    scan1_kernel<<<nchunks, 256, 0, stream>>>(deg, rowptr, bsum);
    scan2_kernel<<<1, 64, 0, stream>>>(bsum, nchunks);
    scan3_kernel<<<(NN + 255) / 256, 256, 0, stream>>>(rowptr, bsum, cursor);
    fill_kernel<<<(ET + 255) / 256, 256, 0, stream>>>(ei, cursor, csr);

    agg1_kernel<<<NN, 128, 0, stream>>>(h1, e_src1, e_dst1, rowptr, deg, csr, b1, hmid);

    gemm2_kernel<<<NN / 8, 320, 0, stream>>>(hmid, W2, h2);
    elogit2_kernel<<<(NN + 255) / 256, 256, 0, stream>>>(h2, a_src2, a_dst2, e_src2, e_dst2);

    agg2_kernel<<<NN, 64, 0, stream>>>(h2, e_src2, e_dst2, rowptr, deg, csr, b2, out);
}

// Round 2
// 548.495 us; speedup vs baseline: 1.0405x; 1.0405x over previous
//
#include <hip/hip_runtime.h>
#include <math.h>

#define NN 50000
#define EE 800000
#define ET (EE + NN)      // edges + self loops
#define F_IN 128
#define HEADS 8
#define HID 16
#define C1 (HEADS * HID)  // 128
#define CLASSES 40
#define NEG_SLOPE 0.2f

// ---------------- GEMM1: h1 = x @ W1   [N,128] x [128,128] ----------------
__global__ void gemm1_kernel(const float* __restrict__ x, const float* __restrict__ W1,
                             float* __restrict__ h1) {
    __shared__ float xs[4][F_IN];
    const int tid = threadIdx.x;
    const int n0 = blockIdx.x * 4;
    for (int idx = tid; idx < 4 * F_IN; idx += 128) {
        int r = idx >> 7, k = idx & 127;
        xs[r][k] = x[(size_t)(n0 + r) * F_IN + k];
    }
    __syncthreads();
    const int r = tid >> 5;
    const int cg = tid & 31;
    float4 acc = make_float4(0.f, 0.f, 0.f, 0.f);
    const float* wp = W1 + 4 * cg;
    #pragma unroll 8
    for (int k = 0; k < F_IN; ++k) {
        float xv = xs[r][k];
        float4 w = *(const float4*)(wp + (size_t)k * C1);
        acc.x += xv * w.x; acc.y += xv * w.y; acc.z += xv * w.z; acc.w += xv * w.w;
    }
    *(float4*)(h1 + (size_t)(n0 + r) * C1 + 4 * cg) = acc;
}

// ---------------- attention logits layer 1 ----------------
__global__ void elogit1_kernel(const float* __restrict__ h1, const float* __restrict__ a_src,
                               const float* __restrict__ a_dst,
                               float* __restrict__ e_src, float* __restrict__ e_dst) {
    int t = blockIdx.x * blockDim.x + threadIdx.x;
    if (t >= NN * HEADS) return;
    int n = t >> 3, hd = t & 7;
    const float* hp = h1 + (size_t)n * C1 + hd * HID;
    const float* as = a_src + hd * HID;
    const float* ad = a_dst + hd * HID;
    float ss = 0.f, sd = 0.f;
    #pragma unroll
    for (int c = 0; c < HID; ++c) {
        float hv = hp[c];
        ss += hv * as[c];
        sd += hv * ad[c];
    }
    e_src[t] = ss;
    e_dst[t] = sd;
}

// ---------------- CSR build ----------------
__global__ void count_kernel(const int* __restrict__ ei, int* __restrict__ deg) {
    int e = blockIdx.x * blockDim.x + threadIdx.x;
    if (e >= ET) return;
    int d = (e < EE) ? ei[EE + e] : (e - EE);
    atomicAdd(&deg[d], 1);
}

__global__ void scan1_kernel(const int* __restrict__ deg, int* __restrict__ rowptr,
                             int* __restrict__ bsum) {
    __shared__ int sh[256];
    const int tid = threadIdx.x;
    const int base = blockIdx.x * 1024 + tid * 4;
    int v[4], s[4];
    #pragma unroll
    for (int j = 0; j < 4; ++j) v[j] = (base + j < NN) ? deg[base + j] : 0;
    s[0] = v[0]; s[1] = s[0] + v[1]; s[2] = s[1] + v[2]; s[3] = s[2] + v[3];
    int T = s[3];
    sh[tid] = T;
    __syncthreads();
    for (int off = 1; off < 256; off <<= 1) {
        int xv = (tid >= off) ? sh[tid - off] : 0;
        __syncthreads();
        sh[tid] += xv;
        __syncthreads();
    }
    int excl = sh[tid] - T;
    #pragma unroll
    for (int j = 0; j < 4; ++j)
        if (base + j < NN) rowptr[base + j] = excl + s[j] - v[j];
    if (tid == 255) bsum[blockIdx.x] = sh[255];
}

__global__ void scan2_kernel(int* __restrict__ bsum, int nchunks) {
    __shared__ int sh[64];
    const int tid = threadIdx.x;
    int v = (tid < nchunks) ? bsum[tid] : 0;
    sh[tid] = v;
    __syncthreads();
    for (int off = 1; off < 64; off <<= 1) {
        int xv = (tid >= off) ? sh[tid - off] : 0;
        __syncthreads();
        sh[tid] += xv;
        __syncthreads();
    }
    if (tid < nchunks) bsum[tid] = sh[tid] - v;  // exclusive
}

__global__ void scan3_kernel(int* __restrict__ rowptr, const int* __restrict__ bsum,
                             int* __restrict__ cursor) {
    int i = blockIdx.x * blockDim.x + threadIdx.x;
    if (i >= NN) return;
    int rp = rowptr[i] + bsum[i >> 10];
    rowptr[i] = rp;
    cursor[i] = rp;
}

// csr2[p] = (src, edge_id)
__global__ void fill_kernel(const int* __restrict__ ei, int* __restrict__ cursor,
                            int2* __restrict__ csr2) {
    int e = blockIdx.x * blockDim.x + threadIdx.x;
    if (e >= ET) return;
    int s, d;
    if (e < EE) { s = ei[e]; d = ei[EE + e]; } else { s = d = e - EE; }
    int p = atomicAdd(&cursor[d], 1);
    csr2[p] = make_int2(s, e);
}

// ---------------- edge weights layer 1: w1[e,h] = exp(lrelu(e_src[s,h]+e_dst[d,h])) ----
__global__ void ew1_kernel(const int* __restrict__ ei, const float* __restrict__ e_src,
                           const float* __restrict__ e_dst, float* __restrict__ w1buf) {
    int t = blockIdx.x * blockDim.x + threadIdx.x;
    if (t >= ET * HEADS) return;
    int e = t >> 3, hd = t & 7;
    int s, d;
    if (e < EE) { s = ei[e]; d = ei[EE + e]; } else { s = d = e - EE; }
    float al = e_src[(size_t)s * HEADS + hd] + e_dst[(size_t)d * HEADS + hd];
    al = (al > 0.f) ? al : NEG_SLOPE * al;
    w1buf[t] = __expf(al);
}

// ---------------- layer-1 aggregation: single pass, precomputed weights ----------------
// one block (128 threads) per dst node; thread = (head = tid>>4, ch = tid&15)
__global__ void agg1_kernel(const float* __restrict__ h1, const float* __restrict__ w1buf,
                            const int* __restrict__ rowptr, const int* __restrict__ deg,
                            const int2* __restrict__ csr2,
                            const float* __restrict__ b1, float* __restrict__ hmid) {
    const int d = blockIdx.x;
    const int tid = threadIdx.x;
    const int hd = tid >> 4;
    const int start = rowptr[d];
    const int cnt = deg[d];

    float denom = 0.f, acc = 0.f;
    for (int i = 0; i < cnt; ++i) {
        int2 se = csr2[start + i];
        float w = w1buf[(size_t)se.y * HEADS + hd];
        denom += w;
        acc += w * h1[(size_t)se.x * C1 + tid];
    }
    float o = acc / (denom + 1e-16f) + b1[tid];
    o = (o > 0.f) ? o : expm1f(o);  // ELU
    hmid[(size_t)d * C1 + tid] = o;
}

// ---------------- GEMM2: h2 = hmid @ W2  [N,128] x [128,40] ----------------
__global__ void gemm2_kernel(const float* __restrict__ hmid, const float* __restrict__ W2,
                             float* __restrict__ h2) {
    __shared__ float xs[8][F_IN];
    const int tid = threadIdx.x;
    const int n0 = blockIdx.x * 8;
    for (int idx = tid; idx < 8 * F_IN; idx += 320) {
        int r = idx >> 7, k = idx & 127;
        xs[r][k] = hmid[(size_t)(n0 + r) * F_IN + k];
    }
    __syncthreads();
    const int r = tid / 40;
    const int c = tid % 40;
    float acc = 0.f;
    #pragma unroll 8
    for (int k = 0; k < F_IN; ++k)
        acc += xs[r][k] * W2[(size_t)k * CLASSES + c];
    h2[(size_t)(n0 + r) * CLASSES + c] = acc;
}

__global__ void elogit2_kernel(const float* __restrict__ h2, const float* __restrict__ a_src,
                               const float* __restrict__ a_dst,
                               float* __restrict__ e_src, float* __restrict__ e_dst) {
    int n = blockIdx.x * blockDim.x + threadIdx.x;
    if (n >= NN) return;
    const float* hp = h2 + (size_t)n * CLASSES;
    float ss = 0.f, sd = 0.f;
    #pragma unroll
    for (int c = 0; c < CLASSES; ++c) {
        float hv = hp[c];
        ss += hv * a_src[c];
        sd += hv * a_dst[c];
    }
    e_src[n] = ss;
    e_dst[n] = sd;
}

// ---------------- edge weights layer 2 ----------------
__global__ void ew2_kernel(const int* __restrict__ ei, const float* __restrict__ e_src,
                           const float* __restrict__ e_dst, float* __restrict__ w2buf) {
    int e = blockIdx.x * blockDim.x + threadIdx.x;
    if (e >= ET) return;
    int s, d;
    if (e < EE) { s = ei[e]; d = ei[EE + e]; } else { s = d = e - EE; }
    float al = e_src[s] + e_dst[d];
    al = (al > 0.f) ? al : NEG_SLOPE * al;
    w2buf[e] = __expf(al);
}

// ---------------- layer-2 aggregation -> output ----------------
__global__ void agg2_kernel(const float* __restrict__ h2, const float* __restrict__ w2buf,
                            const int* __restrict__ rowptr, const int* __restrict__ deg,
                            const int2* __restrict__ csr2,
                            const float* __restrict__ b2, float* __restrict__ out) {
    const int d = blockIdx.x;
    const int c = threadIdx.x;
    const int start = rowptr[d];
    const int cnt = deg[d];

    float denom = 0.f, acc = 0.f;
    for (int i = 0; i < cnt; ++i) {
        int2 se = csr2[start + i];
        float w = w2buf[se.y];
        denom += w;
        if (c < CLASSES) acc += w * h2[(size_t)se.x * CLASSES + c];
    }
    if (c < CLASSES)
        out[(size_t)d * CLASSES + c] = acc / (denom + 1e-16f) + b2[c];
}

extern "C" void kernel_launch(void* const* d_in, const int* in_sizes, int n_in,
                              void* d_out, int out_size, void* d_ws, size_t ws_size,
                              hipStream_t stream) {
    const float* x      = (const float*)d_in[0];
    const int*   ei     = (const int*)d_in[1];
    const float* W1     = (const float*)d_in[2];
    const float* a_src1 = (const float*)d_in[3];
    const float* a_dst1 = (const float*)d_in[4];
    const float* b1     = (const float*)d_in[5];
    const float* W2     = (const float*)d_in[6];
    const float* a_src2 = (const float*)d_in[7];
    const float* a_dst2 = (const float*)d_in[8];
    const float* b2     = (const float*)d_in[9];
    float* out = (float*)d_out;

    char* ws = (char*)d_ws;
    size_t off = 0;
    auto alloc = [&](size_t bytes) { char* p = ws + off; off += (bytes + 255) & ~(size_t)255; return p; };
    float* h1     = (float*)alloc((size_t)NN * C1 * 4);
    float* hmid   = (float*)alloc((size_t)NN * C1 * 4);
    float* h2     = (float*)alloc((size_t)NN * CLASSES * 4);
    float* e_src1 = (float*)alloc((size_t)NN * HEADS * 4);
    float* e_dst1 = (float*)alloc((size_t)NN * HEADS * 4);
    float* e_src2 = (float*)alloc((size_t)NN * 4);
    float* e_dst2 = (float*)alloc((size_t)NN * 4);
    int*   deg    = (int*)alloc((size_t)NN * 4);
    int*   rowptr = (int*)alloc((size_t)NN * 4);
    int*   cursor = (int*)alloc((size_t)NN * 4);
    int2*  csr2   = (int2*)alloc((size_t)ET * 8);
    float* w1buf  = (float*)alloc((size_t)ET * HEADS * 4);
    float* w2buf  = (float*)alloc((size_t)ET * 4);
    int*   bsum   = (int*)alloc(256 * 4);

    hipMemsetAsync(deg, 0, (size_t)NN * 4, stream);

    gemm1_kernel<<<NN / 4, 128, 0, stream>>>(x, W1, h1);
    elogit1_kernel<<<(NN * HEADS + 255) / 256, 256, 0, stream>>>(h1, a_src1, a_dst1, e_src1, e_dst1);

    count_kernel<<<(ET + 255) / 256, 256, 0, stream>>>(ei, deg);
    const int nchunks = (NN + 1023) / 1024;  // 49
    scan1_kernel<<<nchunks, 256, 0, stream>>>(deg, rowptr, bsum);
    scan2_kernel<<<1, 64, 0, stream>>>(bsum, nchunks);
    scan3_kernel<<<(NN + 255) / 256, 256, 0, stream>>>(rowptr, bsum, cursor);
    fill_kernel<<<(ET + 255) / 256, 256, 0, stream>>>(ei, cursor, csr2);

    ew1_kernel<<<(ET * HEADS + 255) / 256, 256, 0, stream>>>(ei, e_src1, e_dst1, w1buf);
    agg1_kernel<<<NN, 128, 0, stream>>>(h1, w1buf, rowptr, deg, csr2, b1, hmid);

    gemm2_kernel<<<NN / 8, 320, 0, stream>>>(hmid, W2, h2);
    elogit2_kernel<<<(NN + 255) / 256, 256, 0, stream>>>(h2, a_src2, a_dst2, e_src2, e_dst2);

    ew2_kernel<<<(ET + 255) / 256, 256, 0, stream>>>(ei, e_src2, e_dst2, w2buf);
    agg2_kernel<<<NN, 64, 0, stream>>>(h2, w2buf, rowptr, deg, csr2, b2, out);
}

// Round 3
// 415.002 us; speedup vs baseline: 1.3752x; 1.3217x over previous
//
#include <hip/hip_runtime.h>
#include <math.h>

#define NN 50000
#define EE 800000
#define ET (EE + NN)      // edges + self loops
#define F_IN 128
#define HEADS 8
#define HID 16
#define C1 (HEADS * HID)  // 128
#define CLASSES 40
#define NEG_SLOPE 0.2f

__device__ __forceinline__ unsigned short f2bf(float f) {
    unsigned u = __float_as_uint(f);
    unsigned r = (u + 0x7fffu + ((u >> 16) & 1u)) >> 16;  // round-to-nearest-even
    return (unsigned short)r;
}
__device__ __forceinline__ float bf2f(unsigned short s) {
    return __uint_as_float(((unsigned)s) << 16);
}
__device__ __forceinline__ float lrelu(float a) {
    return (a > 0.f) ? a : NEG_SLOPE * a;
}

// ---------------- GEMM1 + fused elogit1: h1b(bf16) = x @ W1; e = <h1, a> ----------------
// block = 128 threads, 4 rows; thread = (row r = tid>>5, colgroup cg = tid&31 -> cols 4cg..4cg+3)
__global__ void gemm1_kernel(const float* __restrict__ x, const float* __restrict__ W1,
                             const float* __restrict__ a_src, const float* __restrict__ a_dst,
                             unsigned short* __restrict__ h1b,
                             float* __restrict__ e_src, float* __restrict__ e_dst) {
    __shared__ float xs[4][F_IN];
    const int tid = threadIdx.x;
    const int n0 = blockIdx.x * 4;
    for (int idx = tid; idx < 4 * F_IN; idx += 128) {
        int r = idx >> 7, k = idx & 127;
        xs[r][k] = x[(size_t)(n0 + r) * F_IN + k];
    }
    __syncthreads();
    const int r = tid >> 5;
    const int cg = tid & 31;
    float4 acc = make_float4(0.f, 0.f, 0.f, 0.f);
    const float* wp = W1 + 4 * cg;
    #pragma unroll 8
    for (int k = 0; k < F_IN; ++k) {
        float xv = xs[r][k];
        float4 w = *(const float4*)(wp + (size_t)k * C1);
        acc.x += xv * w.x; acc.y += xv * w.y; acc.z += xv * w.z; acc.w += xv * w.w;
    }
    const int n = n0 + r;
    ushort4 pk;
    pk.x = f2bf(acc.x); pk.y = f2bf(acc.y); pk.z = f2bf(acc.z); pk.w = f2bf(acc.w);
    *(ushort4*)(h1b + (size_t)n * C1 + 4 * cg) = pk;
    // fused attention logits: 4-lane reduction per head (16 ch = 4 colgroups)
    float4 as4 = *(const float4*)(a_src + 4 * cg);
    float4 ad4 = *(const float4*)(a_dst + 4 * cg);
    float ss = acc.x * as4.x + acc.y * as4.y + acc.z * as4.z + acc.w * as4.w;
    float sd = acc.x * ad4.x + acc.y * ad4.y + acc.z * ad4.z + acc.w * ad4.w;
    ss += __shfl_xor(ss, 1); ss += __shfl_xor(ss, 2);
    sd += __shfl_xor(sd, 1); sd += __shfl_xor(sd, 2);
    if ((cg & 3) == 0) {
        e_src[(size_t)n * HEADS + (cg >> 2)] = ss;
        e_dst[(size_t)n * HEADS + (cg >> 2)] = sd;
    }
}

// ---------------- CSR build ----------------
__global__ void count_kernel(const int* __restrict__ ei, int* __restrict__ deg) {
    int e = blockIdx.x * blockDim.x + threadIdx.x;
    if (e >= ET) return;
    int d = (e < EE) ? ei[EE + e] : (e - EE);
    atomicAdd(&deg[d], 1);
}

__global__ void scan1_kernel(const int* __restrict__ deg, int* __restrict__ rowptr,
                             int* __restrict__ bsum) {
    __shared__ int sh[256];
    const int tid = threadIdx.x;
    const int base = blockIdx.x * 1024 + tid * 4;
    int v[4], s[4];
    #pragma unroll
    for (int j = 0; j < 4; ++j) v[j] = (base + j < NN) ? deg[base + j] : 0;
    s[0] = v[0]; s[1] = s[0] + v[1]; s[2] = s[1] + v[2]; s[3] = s[2] + v[3];
    int T = s[3];
    sh[tid] = T;
    __syncthreads();
    for (int off = 1; off < 256; off <<= 1) {
        int xv = (tid >= off) ? sh[tid - off] : 0;
        __syncthreads();
        sh[tid] += xv;
        __syncthreads();
    }
    int excl = sh[tid] - T;
    #pragma unroll
    for (int j = 0; j < 4; ++j)
        if (base + j < NN) rowptr[base + j] = excl + s[j] - v[j];
    if (tid == 255) bsum[blockIdx.x] = sh[255];
}

__global__ void scan2_kernel(int* __restrict__ bsum, int nchunks) {
    __shared__ int sh[64];
    const int tid = threadIdx.x;
    int v = (tid < nchunks) ? bsum[tid] : 0;
    sh[tid] = v;
    __syncthreads();
    for (int off = 1; off < 64; off <<= 1) {
        int xv = (tid >= off) ? sh[tid - off] : 0;
        __syncthreads();
        sh[tid] += xv;
        __syncthreads();
    }
    if (tid < nchunks) bsum[tid] = sh[tid] - v;  // exclusive
}

__global__ void scan3_kernel(int* __restrict__ rowptr, const int* __restrict__ bsum,
                             int* __restrict__ cursor) {
    int i = blockIdx.x * blockDim.x + threadIdx.x;
    if (i >= NN) return;
    int rp = rowptr[i] + bsum[i >> 10];
    rowptr[i] = rp;
    cursor[i] = rp;
}

__global__ void fill_kernel(const int* __restrict__ ei, int* __restrict__ cursor,
                            int* __restrict__ csr) {
    int e = blockIdx.x * blockDim.x + threadIdx.x;
    if (e >= ET) return;
    int s, d;
    if (e < EE) { s = ei[e]; d = ei[EE + e]; } else { s = d = e - EE; }
    int p = atomicAdd(&cursor[d], 1);
    csr[p] = s;
}

// ---------------- layer-1 aggregation: wave per node, 4x edge unroll, inline weights ----
// block = 256 = 4 nodes; lane t owns channels 2t,2t+1 (same head = t>>3)
__global__ void agg1_kernel(const unsigned short* __restrict__ h1b,
                            const float* __restrict__ e_src, const float* __restrict__ e_dst,
                            const int* __restrict__ rowptr, const int* __restrict__ deg,
                            const int* __restrict__ csr,
                            const float* __restrict__ b1, float* __restrict__ hmid) {
    const int d = blockIdx.x * 4 + (threadIdx.x >> 6);
    const int lane = threadIdx.x & 63;
    const int hd = lane >> 3;
    const float ed = e_dst[(size_t)d * HEADS + hd];
    const int start = rowptr[d];
    const int cnt = deg[d];

    float denom = 0.f, acc0 = 0.f, acc1 = 0.f;
    int i = 0;
    for (; i + 4 <= cnt; i += 4) {
        int s0 = csr[start + i];
        int s1 = csr[start + i + 1];
        int s2 = csr[start + i + 2];
        int s3 = csr[start + i + 3];
        float es0 = e_src[(size_t)s0 * HEADS + hd];
        float es1 = e_src[(size_t)s1 * HEADS + hd];
        float es2 = e_src[(size_t)s2 * HEADS + hd];
        float es3 = e_src[(size_t)s3 * HEADS + hd];
        unsigned g0 = *(const unsigned*)(h1b + (size_t)s0 * C1 + 2 * lane);
        unsigned g1 = *(const unsigned*)(h1b + (size_t)s1 * C1 + 2 * lane);
        unsigned g2 = *(const unsigned*)(h1b + (size_t)s2 * C1 + 2 * lane);
        unsigned g3 = *(const unsigned*)(h1b + (size_t)s3 * C1 + 2 * lane);
        float w0 = __expf(lrelu(es0 + ed));
        float w1 = __expf(lrelu(es1 + ed));
        float w2 = __expf(lrelu(es2 + ed));
        float w3 = __expf(lrelu(es3 + ed));
        denom += (w0 + w1) + (w2 + w3);
        acc0 += w0 * __uint_as_float(g0 << 16) + w1 * __uint_as_float(g1 << 16)
              + w2 * __uint_as_float(g2 << 16) + w3 * __uint_as_float(g3 << 16);
        acc1 += w0 * __uint_as_float(g0 & 0xffff0000u) + w1 * __uint_as_float(g1 & 0xffff0000u)
              + w2 * __uint_as_float(g2 & 0xffff0000u) + w3 * __uint_as_float(g3 & 0xffff0000u);
    }
    for (; i < cnt; ++i) {
        int s0 = csr[start + i];
        float es0 = e_src[(size_t)s0 * HEADS + hd];
        unsigned g0 = *(const unsigned*)(h1b + (size_t)s0 * C1 + 2 * lane);
        float w0 = __expf(lrelu(es0 + ed));
        denom += w0;
        acc0 += w0 * __uint_as_float(g0 << 16);
        acc1 += w0 * __uint_as_float(g0 & 0xffff0000u);
    }
    float inv = 1.f / (denom + 1e-16f);
    float o0 = acc0 * inv + b1[2 * lane];
    float o1 = acc1 * inv + b1[2 * lane + 1];
    o0 = (o0 > 0.f) ? o0 : expm1f(o0);
    o1 = (o1 > 0.f) ? o1 : expm1f(o1);
    *(float2*)(hmid + (size_t)d * C1 + 2 * lane) = make_float2(o0, o1);
}

// ---------------- GEMM2: h2 = hmid @ W2  [N,128] x [128,40] ----------------
__global__ void gemm2_kernel(const float* __restrict__ hmid, const float* __restrict__ W2,
                             float* __restrict__ h2) {
    __shared__ float xs[8][F_IN];
    const int tid = threadIdx.x;
    const int n0 = blockIdx.x * 8;
    for (int idx = tid; idx < 8 * F_IN; idx += 320) {
        int r = idx >> 7, k = idx & 127;
        xs[r][k] = hmid[(size_t)(n0 + r) * F_IN + k];
    }
    __syncthreads();
    const int r = tid / 40;
    const int c = tid % 40;
    float acc = 0.f;
    #pragma unroll 8
    for (int k = 0; k < F_IN; ++k)
        acc += xs[r][k] * W2[(size_t)k * CLASSES + c];
    h2[(size_t)(n0 + r) * CLASSES + c] = acc;
}

__global__ void elogit2_kernel(const float* __restrict__ h2, const float* __restrict__ a_src,
                               const float* __restrict__ a_dst,
                               float* __restrict__ e_src, float* __restrict__ e_dst) {
    int n = blockIdx.x * blockDim.x + threadIdx.x;
    if (n >= NN) return;
    const float* hp = h2 + (size_t)n * CLASSES;
    float ss = 0.f, sd = 0.f;
    #pragma unroll
    for (int c = 0; c < CLASSES; ++c) {
        float hv = hp[c];
        ss += hv * a_src[c];
        sd += hv * a_dst[c];
    }
    e_src[n] = ss;
    e_dst[n] = sd;
}

// ---------------- layer-2 aggregation -> output: wave per node, 4x unroll ----------------
__global__ void agg2_kernel(const float* __restrict__ h2,
                            const float* __restrict__ e_src, const float* __restrict__ e_dst,
                            const int* __restrict__ rowptr, const int* __restrict__ deg,
                            const int* __restrict__ csr,
                            const float* __restrict__ b2, float* __restrict__ out) {
    const int d = blockIdx.x * 4 + (threadIdx.x >> 6);
    const int lane = threadIdx.x & 63;
    const bool act = lane < CLASSES;
    const float ed = e_dst[d];
    const int start = rowptr[d];
    const int cnt = deg[d];

    float denom = 0.f, acc = 0.f;
    int i = 0;
    for (; i + 4 <= cnt; i += 4) {
        int s0 = csr[start + i];
        int s1 = csr[start + i + 1];
        int s2 = csr[start + i + 2];
        int s3 = csr[start + i + 3];
        float es0 = e_src[s0], es1 = e_src[s1], es2 = e_src[s2], es3 = e_src[s3];
        float w0 = __expf(lrelu(es0 + ed));
        float w1 = __expf(lrelu(es1 + ed));
        float w2 = __expf(lrelu(es2 + ed));
        float w3 = __expf(lrelu(es3 + ed));
        denom += (w0 + w1) + (w2 + w3);
        if (act) {
            acc += w0 * h2[(size_t)s0 * CLASSES + lane] + w1 * h2[(size_t)s1 * CLASSES + lane]
                 + w2 * h2[(size_t)s2 * CLASSES + lane] + w3 * h2[(size_t)s3 * CLASSES + lane];
        }
    }
    for (; i < cnt; ++i) {
        int s0 = csr[start + i];
        float w0 = __expf(lrelu(e_src[s0] + ed));
        denom += w0;
        if (act) acc += w0 * h2[(size_t)s0 * CLASSES + lane];
    }
    if (act)
        out[(size_t)d * CLASSES + lane] = acc / (denom + 1e-16f) + b2[lane];
}

extern "C" void kernel_launch(void* const* d_in, const int* in_sizes, int n_in,
                              void* d_out, int out_size, void* d_ws, size_t ws_size,
                              hipStream_t stream) {
    const float* x      = (const float*)d_in[0];
    const int*   ei     = (const int*)d_in[1];
    const float* W1     = (const float*)d_in[2];
    const float* a_src1 = (const float*)d_in[3];
    const float* a_dst1 = (const float*)d_in[4];
    const float* b1     = (const float*)d_in[5];
    const float* W2     = (const float*)d_in[6];
    const float* a_src2 = (const float*)d_in[7];
    const float* a_dst2 = (const float*)d_in[8];
    const float* b2     = (const float*)d_in[9];
    float* out = (float*)d_out;

    char* ws = (char*)d_ws;
    size_t off = 0;
    auto alloc = [&](size_t bytes) { char* p = ws + off; off += (bytes + 255) & ~(size_t)255; return p; };
    unsigned short* h1b = (unsigned short*)alloc((size_t)NN * C1 * 2);
    float* hmid   = (float*)alloc((size_t)NN * C1 * 4);
    float* h2     = (float*)alloc((size_t)NN * CLASSES * 4);
    float* e_src1 = (float*)alloc((size_t)NN * HEADS * 4);
    float* e_dst1 = (float*)alloc((size_t)NN * HEADS * 4);
    float* e_src2 = (float*)alloc((size_t)NN * 4);
    float* e_dst2 = (float*)alloc((size_t)NN * 4);
    int*   deg    = (int*)alloc((size_t)NN * 4);
    int*   rowptr = (int*)alloc((size_t)NN * 4);
    int*   cursor = (int*)alloc((size_t)NN * 4);
    int*   csr    = (int*)alloc((size_t)ET * 4);
    int*   bsum   = (int*)alloc(256 * 4);

    hipMemsetAsync(deg, 0, (size_t)NN * 4, stream);

    gemm1_kernel<<<NN / 4, 128, 0, stream>>>(x, W1, a_src1, a_dst1, h1b, e_src1, e_dst1);

    count_kernel<<<(ET + 255) / 256, 256, 0, stream>>>(ei, deg);
    const int nchunks = (NN + 1023) / 1024;  // 49
    scan1_kernel<<<nchunks, 256, 0, stream>>>(deg, rowptr, bsum);
    scan2_kernel<<<1, 64, 0, stream>>>(bsum, nchunks);
    scan3_kernel<<<(NN + 255) / 256, 256, 0, stream>>>(rowptr, bsum, cursor);
    fill_kernel<<<(ET + 255) / 256, 256, 0, stream>>>(ei, cursor, csr);

    agg1_kernel<<<NN / 4, 256, 0, stream>>>(h1b, e_src1, e_dst1, rowptr, deg, csr, b1, hmid);

    gemm2_kernel<<<NN / 8, 320, 0, stream>>>(hmid, W2, h2);
    elogit2_kernel<<<(NN + 255) / 256, 256, 0, stream>>>(h2, a_src2, a_dst2, e_src2, e_dst2);

    agg2_kernel<<<NN / 4, 256, 0, stream>>>(h2, e_src2, e_dst2, rowptr, deg, csr, b2, out);
}

// Round 5
// 315.161 us; speedup vs baseline: 1.8108x; 1.3168x over previous
//
#include <hip/hip_runtime.h>
#include <math.h>

#define NN 50000
#define EE 800000
#define ET (EE + NN)      // edges + self loops
#define F_IN 128
#define HEADS 8
#define HID 16
#define C1 (HEADS * HID)  // 128
#define CLASSES 40
#define NEG_SLOPE 0.2f

typedef __attribute__((ext_vector_type(8))) short bf16x8;
typedef __attribute__((ext_vector_type(4))) float f32x4;

__device__ __forceinline__ unsigned short f2bf(float f) {
    unsigned u = __float_as_uint(f);
    unsigned r = (u + 0x7fffu + ((u >> 16) & 1u)) >> 16;  // round-to-nearest-even
    return (unsigned short)r;
}
__device__ __forceinline__ float bf2f(unsigned short s) {
    return __uint_as_float(((unsigned)s) << 16);
}
__device__ __forceinline__ float lrelu(float a) {
    return (a > 0.f) ? a : NEG_SLOPE * a;
}

// ---------------- GEMM1 (MFMA bf16): h1b = bf16(x @ W1) ----------------
// block = 256 (4 waves). Wave w owns cols [32w, 32w+32) = 2 N-tiles; B-frags in regs.
// Block processes 2 M-tiles (32 rows). D layout: col=lane&15, row=(lane>>4)*4+reg.
__global__ void gemm1_kernel(const float* __restrict__ x, const float* __restrict__ W1,
                             unsigned short* __restrict__ h1b) {
    const int tid = threadIdx.x;
    const int w = tid >> 6, lane = tid & 63;
    const int q = lane >> 4, c = lane & 15;

    bf16x8 bfrag[2][4];
    #pragma unroll
    for (int nt = 0; nt < 2; ++nt) {
        const int col = w * 32 + nt * 16 + c;
        #pragma unroll
        for (int kc = 0; kc < 4; ++kc) {
            const int k0 = kc * 32 + q * 8;
            bf16x8 bb;
            #pragma unroll
            for (int j = 0; j < 8; ++j)
                bb[j] = (short)f2bf(W1[(size_t)(k0 + j) * C1 + col]);
            bfrag[nt][kc] = bb;
        }
    }

    #pragma unroll
    for (int mt = 0; mt < 2; ++mt) {
        const int m0 = (blockIdx.x * 2 + mt) * 16;
        if (m0 >= NN) break;
        int row = m0 + c;
        if (row > NN - 1) row = NN - 1;
        bf16x8 afrag[4];
        #pragma unroll
        for (int kc = 0; kc < 4; ++kc) {
            const float* xp = x + (size_t)row * F_IN + kc * 32 + q * 8;
            float4 p0 = *(const float4*)xp;
            float4 p1 = *(const float4*)(xp + 4);
            bf16x8 aa;
            aa[0] = (short)f2bf(p0.x); aa[1] = (short)f2bf(p0.y);
            aa[2] = (short)f2bf(p0.z); aa[3] = (short)f2bf(p0.w);
            aa[4] = (short)f2bf(p1.x); aa[5] = (short)f2bf(p1.y);
            aa[6] = (short)f2bf(p1.z); aa[7] = (short)f2bf(p1.w);
            afrag[kc] = aa;
        }
        f32x4 acc0 = {0.f, 0.f, 0.f, 0.f};
        f32x4 acc1 = {0.f, 0.f, 0.f, 0.f};
        #pragma unroll
        for (int kc = 0; kc < 4; ++kc) {
            acc0 = __builtin_amdgcn_mfma_f32_16x16x32_bf16(afrag[kc], bfrag[0][kc], acc0, 0, 0, 0);
            acc1 = __builtin_amdgcn_mfma_f32_16x16x32_bf16(afrag[kc], bfrag[1][kc], acc1, 0, 0, 0);
        }
        #pragma unroll
        for (int r = 0; r < 4; ++r) {
            const int ro = m0 + q * 4 + r;
            if (ro < NN) {
                h1b[(size_t)ro * C1 + w * 32 + c]      = f2bf(acc0[r]);
                h1b[(size_t)ro * C1 + w * 32 + 16 + c] = f2bf(acc1[r]);
            }
        }
    }
}

// ---------------- elogit1: per (node, head) dot with a_src/a_dst ----------------
__global__ void elogit1_kernel(const unsigned short* __restrict__ h1b,
                               const float* __restrict__ a_src, const float* __restrict__ a_dst,
                               float* __restrict__ e_src, float* __restrict__ e_dst) {
    int t = blockIdx.x * blockDim.x + threadIdx.x;
    if (t >= NN * HEADS) return;
    int n = t >> 3, hd = t & 7;
    const uint4* hp = (const uint4*)(h1b + (size_t)n * C1 + hd * HID);
    uint4 g0 = hp[0], g1 = hp[1];
    const float* as = a_src + hd * HID;
    const float* ad = a_dst + hd * HID;
    unsigned gs[8] = {g0.x, g0.y, g0.z, g0.w, g1.x, g1.y, g1.z, g1.w};
    float ss = 0.f, sd = 0.f;
    #pragma unroll
    for (int j = 0; j < 8; ++j) {
        float lo = __uint_as_float(gs[j] << 16);
        float hi = __uint_as_float(gs[j] & 0xffff0000u);
        ss += lo * as[2 * j] + hi * as[2 * j + 1];
        sd += lo * ad[2 * j] + hi * ad[2 * j + 1];
    }
    e_src[t] = ss;
    e_dst[t] = sd;
}

// ---------------- CSR build ----------------
__global__ void count_kernel(const int* __restrict__ ei, int* __restrict__ deg) {
    int e = blockIdx.x * blockDim.x + threadIdx.x;
    if (e >= ET) return;
    int d = (e < EE) ? ei[EE + e] : (e - EE);
    atomicAdd(&deg[d], 1);
}

__global__ void scan1_kernel(const int* __restrict__ deg, int* __restrict__ rowptr,
                             int* __restrict__ bsum) {
    __shared__ int sh[256];
    const int tid = threadIdx.x;
    const int base = blockIdx.x * 1024 + tid * 4;
    int v[4], s[4];
    #pragma unroll
    for (int j = 0; j < 4; ++j) v[j] = (base + j < NN) ? deg[base + j] : 0;
    s[0] = v[0]; s[1] = s[0] + v[1]; s[2] = s[1] + v[2]; s[3] = s[2] + v[3];
    int T = s[3];
    sh[tid] = T;
    __syncthreads();
    for (int off = 1; off < 256; off <<= 1) {
        int xv = (tid >= off) ? sh[tid - off] : 0;
        __syncthreads();
        sh[tid] += xv;
        __syncthreads();
    }
    int excl = sh[tid] - T;
    #pragma unroll
    for (int j = 0; j < 4; ++j)
        if (base + j < NN) rowptr[base + j] = excl + s[j] - v[j];
    if (tid == 255) bsum[blockIdx.x] = sh[255];
}

__global__ void scan2_kernel(int* __restrict__ bsum, int nchunks) {
    __shared__ int sh[64];
    const int tid = threadIdx.x;
    int v = (tid < nchunks) ? bsum[tid] : 0;
    sh[tid] = v;
    __syncthreads();
    for (int off = 1; off < 64; off <<= 1) {
        int xv = (tid >= off) ? sh[tid - off] : 0;
        __syncthreads();
        sh[tid] += xv;
        __syncthreads();
    }
    if (tid < nchunks) bsum[tid] = sh[tid] - v;  // exclusive
}

__global__ void scan3_kernel(int* __restrict__ rowptr, const int* __restrict__ bsum,
                             int* __restrict__ cursor) {
    int i = blockIdx.x * blockDim.x + threadIdx.x;
    if (i >= NN) return;
    int rp = rowptr[i] + bsum[i >> 10];
    rowptr[i] = rp;
    cursor[i] = rp;
}

__global__ void fill_kernel(const int* __restrict__ ei, int* __restrict__ cursor,
                            int* __restrict__ csr) {
    int e = blockIdx.x * blockDim.x + threadIdx.x;
    if (e >= ET) return;
    int s, d;
    if (e < EE) { s = ei[e]; d = ei[EE + e]; } else { s = d = e - EE; }
    int p = atomicAdd(&cursor[d], 1);
    csr[p] = s;
}

// ---------------- layer-1 aggregation: wave per node, 4x edge unroll ----------------
__global__ void agg1_kernel(const unsigned short* __restrict__ h1b,
                            const float* __restrict__ e_src, const float* __restrict__ e_dst,
                            const int* __restrict__ rowptr, const int* __restrict__ deg,
                            const int* __restrict__ csr,
                            const float* __restrict__ b1, float* __restrict__ hmid) {
    const int d = blockIdx.x * 4 + (threadIdx.x >> 6);
    const int lane = threadIdx.x & 63;
    const int hd = lane >> 3;
    const float ed = e_dst[(size_t)d * HEADS + hd];
    const int start = rowptr[d];
    const int cnt = deg[d];

    float denom = 0.f, acc0 = 0.f, acc1 = 0.f;
    int i = 0;
    for (; i + 4 <= cnt; i += 4) {
        int s0 = csr[start + i];
        int s1 = csr[start + i + 1];
        int s2 = csr[start + i + 2];
        int s3 = csr[start + i + 3];
        float es0 = e_src[(size_t)s0 * HEADS + hd];
        float es1 = e_src[(size_t)s1 * HEADS + hd];
        float es2 = e_src[(size_t)s2 * HEADS + hd];
        float es3 = e_src[(size_t)s3 * HEADS + hd];
        unsigned g0 = *(const unsigned*)(h1b + (size_t)s0 * C1 + 2 * lane);
        unsigned g1 = *(const unsigned*)(h1b + (size_t)s1 * C1 + 2 * lane);
        unsigned g2 = *(const unsigned*)(h1b + (size_t)s2 * C1 + 2 * lane);
        unsigned g3 = *(const unsigned*)(h1b + (size_t)s3 * C1 + 2 * lane);
        float w0 = __expf(lrelu(es0 + ed));
        float w1 = __expf(lrelu(es1 + ed));
        float w2 = __expf(lrelu(es2 + ed));
        float w3 = __expf(lrelu(es3 + ed));
        denom += (w0 + w1) + (w2 + w3);
        acc0 += w0 * __uint_as_float(g0 << 16) + w1 * __uint_as_float(g1 << 16)
              + w2 * __uint_as_float(g2 << 16) + w3 * __uint_as_float(g3 << 16);
        acc1 += w0 * __uint_as_float(g0 & 0xffff0000u) + w1 * __uint_as_float(g1 & 0xffff0000u)
              + w2 * __uint_as_float(g2 & 0xffff0000u) + w3 * __uint_as_float(g3 & 0xffff0000u);
    }
    for (; i < cnt; ++i) {
        int s0 = csr[start + i];
        float es0 = e_src[(size_t)s0 * HEADS + hd];
        unsigned g0 = *(const unsigned*)(h1b + (size_t)s0 * C1 + 2 * lane);
        float w0 = __expf(lrelu(es0 + ed));
        denom += w0;
        acc0 += w0 * __uint_as_float(g0 << 16);
        acc1 += w0 * __uint_as_float(g0 & 0xffff0000u);
    }
    float inv = 1.f / (denom + 1e-16f);
    float o0 = acc0 * inv + b1[2 * lane];
    float o1 = acc1 * inv + b1[2 * lane + 1];
    o0 = (o0 > 0.f) ? o0 : expm1f(o0);
    o1 = (o1 > 0.f) ? o1 : expm1f(o1);
    *(float2*)(hmid + (size_t)d * C1 + 2 * lane) = make_float2(o0, o1);
}

// ---------------- GEMM2 (MFMA bf16): h2b = bf16(hmid @ W2) ----------------
// block = 256 (4 waves); wave w owns M-tile (blockIdx*4+w); 3 N-tiles cover 48>=40 cols.
__global__ void gemm2_kernel(const float* __restrict__ hmid, const float* __restrict__ W2,
                             unsigned short* __restrict__ h2b) {
    const int tid = threadIdx.x;
    const int w = tid >> 6, lane = tid & 63;
    const int q = lane >> 4, c = lane & 15;

    bf16x8 bfrag[3][4];
    #pragma unroll
    for (int nt = 0; nt < 3; ++nt) {
        const int col = nt * 16 + c;
        const bool cv = col < CLASSES;
        #pragma unroll
        for (int kc = 0; kc < 4; ++kc) {
            const int k0 = kc * 32 + q * 8;
            bf16x8 bb;
            #pragma unroll
            for (int j = 0; j < 8; ++j)
                bb[j] = cv ? (short)f2bf(W2[(size_t)(k0 + j) * CLASSES + col]) : (short)0;
            bfrag[nt][kc] = bb;
        }
    }

    const int m0 = (blockIdx.x * 4 + w) * 16;
    if (m0 >= NN) return;
    int row = m0 + c;
    if (row > NN - 1) row = NN - 1;
    bf16x8 afrag[4];
    #pragma unroll
    for (int kc = 0; kc < 4; ++kc) {
        const float* xp = hmid + (size_t)row * F_IN + kc * 32 + q * 8;
        float4 p0 = *(const float4*)xp;
        float4 p1 = *(const float4*)(xp + 4);
        bf16x8 aa;
        aa[0] = (short)f2bf(p0.x); aa[1] = (short)f2bf(p0.y);
        aa[2] = (short)f2bf(p0.z); aa[3] = (short)f2bf(p0.w);
        aa[4] = (short)f2bf(p1.x); aa[5] = (short)f2bf(p1.y);
        aa[6] = (short)f2bf(p1.z); aa[7] = (short)f2bf(p1.w);
        afrag[kc] = aa;
    }
    f32x4 acc[3] = {{0.f,0.f,0.f,0.f},{0.f,0.f,0.f,0.f},{0.f,0.f,0.f,0.f}};
    #pragma unroll
    for (int kc = 0; kc < 4; ++kc) {
        acc[0] = __builtin_amdgcn_mfma_f32_16x16x32_bf16(afrag[kc], bfrag[0][kc], acc[0], 0, 0, 0);
        acc[1] = __builtin_amdgcn_mfma_f32_16x16x32_bf16(afrag[kc], bfrag[1][kc], acc[1], 0, 0, 0);
        acc[2] = __builtin_amdgcn_mfma_f32_16x16x32_bf16(afrag[kc], bfrag[2][kc], acc[2], 0, 0, 0);
    }
    #pragma unroll
    for (int nt = 0; nt < 3; ++nt) {
        const int col = nt * 16 + c;
        if (col >= CLASSES) continue;
        #pragma unroll
        for (int r = 0; r < 4; ++r) {
            const int ro = m0 + q * 4 + r;
            if (ro < NN) h2b[(size_t)ro * CLASSES + col] = f2bf(acc[nt][r]);
        }
    }
}

// ---------------- elogit2 ----------------
__global__ void elogit2_kernel(const unsigned short* __restrict__ h2b,
                               const float* __restrict__ a_src, const float* __restrict__ a_dst,
                               float* __restrict__ e_src, float* __restrict__ e_dst) {
    int n = blockIdx.x * blockDim.x + threadIdx.x;
    if (n >= NN) return;
    const unsigned* hp = (const unsigned*)(h2b + (size_t)n * CLASSES);
    float ss = 0.f, sd = 0.f;
    #pragma unroll
    for (int j = 0; j < CLASSES / 2; ++j) {
        unsigned g = hp[j];
        float lo = __uint_as_float(g << 16);
        float hi = __uint_as_float(g & 0xffff0000u);
        ss += lo * a_src[2 * j] + hi * a_src[2 * j + 1];
        sd += lo * a_dst[2 * j] + hi * a_dst[2 * j + 1];
    }
    e_src[n] = ss;
    e_dst[n] = sd;
}

// ---------------- layer-2 aggregation -> output: wave per node, 4x unroll, bf16 gathers ---
__global__ void agg2_kernel(const unsigned short* __restrict__ h2b,
                            const float* __restrict__ e_src, const float* __restrict__ e_dst,
                            const int* __restrict__ rowptr, const int* __restrict__ deg,
                            const int* __restrict__ csr,
                            const float* __restrict__ b2, float* __restrict__ out) {
    const int d = blockIdx.x * 4 + (threadIdx.x >> 6);
    const int lane = threadIdx.x & 63;
    const bool act = lane < CLASSES / 2;  // lanes 0..19 own cols 2l,2l+1
    const float ed = e_dst[d];
    const int start = rowptr[d];
    const int cnt = deg[d];

    float denom = 0.f, acc0 = 0.f, acc1 = 0.f;
    int i = 0;
    for (; i + 4 <= cnt; i += 4) {
        int s0 = csr[start + i];
        int s1 = csr[start + i + 1];
        int s2 = csr[start + i + 2];
        int s3 = csr[start + i + 3];
        float es0 = e_src[s0], es1 = e_src[s1], es2 = e_src[s2], es3 = e_src[s3];
        unsigned g0 = 0, g1 = 0, g2 = 0, g3 = 0;
        if (act) {
            g0 = *(const unsigned*)(h2b + (size_t)s0 * CLASSES + 2 * lane);
            g1 = *(const unsigned*)(h2b + (size_t)s1 * CLASSES + 2 * lane);
            g2 = *(const unsigned*)(h2b + (size_t)s2 * CLASSES + 2 * lane);
            g3 = *(const unsigned*)(h2b + (size_t)s3 * CLASSES + 2 * lane);
        }
        float w0 = __expf(lrelu(es0 + ed));
        float w1 = __expf(lrelu(es1 + ed));
        float w2 = __expf(lrelu(es2 + ed));
        float w3 = __expf(lrelu(es3 + ed));
        denom += (w0 + w1) + (w2 + w3);
        acc0 += w0 * __uint_as_float(g0 << 16) + w1 * __uint_as_float(g1 << 16)
              + w2 * __uint_as_float(g2 << 16) + w3 * __uint_as_float(g3 << 16);
        acc1 += w0 * __uint_as_float(g0 & 0xffff0000u) + w1 * __uint_as_float(g1 & 0xffff0000u)
              + w2 * __uint_as_float(g2 & 0xffff0000u) + w3 * __uint_as_float(g3 & 0xffff0000u);
    }
    for (; i < cnt; ++i) {
        int s0 = csr[start + i];
        float w0 = __expf(lrelu(e_src[s0] + ed));
        unsigned g0 = act ? *(const unsigned*)(h2b + (size_t)s0 * CLASSES + 2 * lane) : 0;
        denom += w0;
        acc0 += w0 * __uint_as_float(g0 << 16);
        acc1 += w0 * __uint_as_float(g0 & 0xffff0000u);
    }
    if (act) {
        float inv = 1.f / (denom + 1e-16f);
        out[(size_t)d * CLASSES + 2 * lane]     = acc0 * inv + b2[2 * lane];
        out[(size_t)d * CLASSES + 2 * lane + 1] = acc1 * inv + b2[2 * lane + 1];
    }
}

extern "C" void kernel_launch(void* const* d_in, const int* in_sizes, int n_in,
                              void* d_out, int out_size, void* d_ws, size_t ws_size,
                              hipStream_t stream) {
    const float* x      = (const float*)d_in[0];
    const int*   ei     = (const int*)d_in[1];
    const float* W1     = (const float*)d_in[2];
    const float* a_src1 = (const float*)d_in[3];
    const float* a_dst1 = (const float*)d_in[4];
    const float* b1     = (const float*)d_in[5];
    const float* W2     = (const float*)d_in[6];
    const float* a_src2 = (const float*)d_in[7];
    const float* a_dst2 = (const float*)d_in[8];
    const float* b2     = (const float*)d_in[9];
    float* out = (float*)d_out;

    char* ws = (char*)d_ws;
    size_t off = 0;
    auto alloc = [&](size_t bytes) { char* p = ws + off; off += (bytes + 255) & ~(size_t)255; return p; };
    unsigned short* h1b = (unsigned short*)alloc((size_t)NN * C1 * 2);
    unsigned short* h2b = (unsigned short*)alloc((size_t)NN * CLASSES * 2);
    float* hmid   = (float*)alloc((size_t)NN * C1 * 4);
    float* e_src1 = (float*)alloc((size_t)NN * HEADS * 4);
    float* e_dst1 = (float*)alloc((size_t)NN * HEADS * 4);
    float* e_src2 = (float*)alloc((size_t)NN * 4);
    float* e_dst2 = (float*)alloc((size_t)NN * 4);
    int*   deg    = (int*)alloc((size_t)NN * 4);
    int*   rowptr = (int*)alloc((size_t)NN * 4);
    int*   cursor = (int*)alloc((size_t)NN * 4);
    int*   csr    = (int*)alloc((size_t)ET * 4);
    int*   bsum   = (int*)alloc(256 * 4);

    hipMemsetAsync(deg, 0, (size_t)NN * 4, stream);

    gemm1_kernel<<<(NN + 31) / 32, 256, 0, stream>>>(x, W1, h1b);
    elogit1_kernel<<<(NN * HEADS + 255) / 256, 256, 0, stream>>>(h1b, a_src1, a_dst1, e_src1, e_dst1);

    count_kernel<<<(ET + 255) / 256, 256, 0, stream>>>(ei, deg);
    const int nchunks = (NN + 1023) / 1024;  // 49
    scan1_kernel<<<nchunks, 256, 0, stream>>>(deg, rowptr, bsum);
    scan2_kernel<<<1, 64, 0, stream>>>(bsum, nchunks);
    scan3_kernel<<<(NN + 255) / 256, 256, 0, stream>>>(rowptr, bsum, cursor);
    fill_kernel<<<(ET + 255) / 256, 256, 0, stream>>>(ei, cursor, csr);

    agg1_kernel<<<NN / 4, 256, 0, stream>>>(h1b, e_src1, e_dst1, rowptr, deg, csr, b1, hmid);

    gemm2_kernel<<<(NN + 63) / 64, 256, 0, stream>>>(hmid, W2, h2b);
    elogit2_kernel<<<(NN + 255) / 256, 256, 0, stream>>>(h2b, a_src2, a_dst2, e_src2, e_dst2);

    agg2_kernel<<<NN / 4, 256, 0, stream>>>(h2b, e_src2, e_dst2, rowptr, deg, csr, b2, out);
}